// Round 16
// baseline (864.128 us; speedup 1.0000x reference)
//
#include <hip/hip_runtime.h>
#include <hip/hip_bf16.h>

// SPINN: word GEMM + XCD-sharded persistent TreeLSTM.
// r16: tail levels (nr<128) switch from per-level barriers to PER-NODE dataflow
// flags: producer tiles atomicAdd a node counter (target 32 u-blocks) after
// vmcnt-drained stores; consumer tiles spin only on their own 32 children.
// Tree-depth pipeline replaces ~35 barrier rounds. Big levels keep tile64+barrier.
// B=128, L=64, E=512, H=512, T=127.

#define Bn 128
#define Ln 64
#define En 512
#define Hn 512
#define Tn 127
#define LEAF_ROWS (Bn*Ln)
#define NODE_ROWS (Bn*(Ln-1))
#define TOT_ROWS (LEAF_ROWS+NODE_ROWS)
#define NLVL 64
#define NXCD 8
#define CAPX 512                 // max rows per XCD-bin per level
#define NBLK 512                 // 2 blocks/CU
#define FPAD 16
#define MAXRANK 96
#define SPIN_CAP (1<<22)
#define WSPIN (1<<20)
#define GATE_STRIDE (512*1024)
#define WLDS_BYTES 65536         // 2 gates x 16u x 1024k x 2B
#define PART_BYTES (4*2*16*20*4) // [wave][gatepair][row][col+pad] f32
#define DYN_BYTES (WLDS_BYTES + PART_BYTES)

// barrier/census state layout (ints), zeroed by precompute_ctrl each call
#define OFF_CENSUS 0                              // NXCD*FPAD
#define OFF_RANK   (OFF_CENSUS + NXCD*FPAD)       // NBLK*FPAD
#define OFF_SFLAG  (OFF_RANK + NBLK*FPAD)         // NBLK*FPAD
#define OFF_SGEN   (OFF_SFLAG + NBLK*FPAD)        // FPAD
#define OFF_FX     (OFF_SGEN + FPAD)              // NXCD*MAXRANK*FPAD
#define OFF_GX     (OFF_FX + NXCD*MAXRANK*FPAD)   // NXCD*FPAD
#define BAR_INTS   (OFF_GX + NXCD*FPAD)

typedef __attribute__((ext_vector_type(8))) short bf16x8;
typedef __attribute__((ext_vector_type(4))) float f32x4;

static __device__ __forceinline__ float bf2f(unsigned short u){
  unsigned v = ((unsigned)u) << 16;
  float f; __builtin_memcpy(&f, &v, 4); return f;
}
static __device__ __forceinline__ unsigned short f2bf(float f){
  unsigned u; __builtin_memcpy(&u, &f, 4);
  u = u + 0x7FFFu + ((u >> 16) & 1u);   // round-nearest-even
  return (unsigned short)(u >> 16);
}
static __device__ __forceinline__ float sigm(float x){
  return 1.0f / (1.0f + __expf(-x));
}
static __device__ __forceinline__ float tanh_fast(float x){
  x = fminf(fmaxf(x, -15.0f), 15.0f);
  float t = __expf(2.0f * x);
  return (t - 1.0f) / (t + 1.0f);
}
static __device__ __forceinline__ int xcc_id(){
  unsigned v;
  asm volatile("s_getreg_b32 %0, hwreg(HW_REG_XCC_ID)" : "=s"(v));
  return (int)(v & 7);
}

// Per-XCD fence-free barrier (r7-proven, r12 form).
static __device__ __forceinline__ void xcd_barrier(int* bar, int x, int rank, int nx, int epoch){
  __syncthreads();
  int* fx = bar + OFF_FX + x * MAXRANK * FPAD;
  int* gx = bar + OFF_GX + x * FPAD;
  int nxl = min(nx, MAXRANK);
  if (rank == 0){
    for (int i = threadIdx.x + 1; i < nxl; i += 256){
      int c = 0;
      while (__hip_atomic_load(&fx[i * FPAD], __ATOMIC_RELAXED, __HIP_MEMORY_SCOPE_AGENT) < epoch && c < SPIN_CAP){
        __builtin_amdgcn_s_sleep(1); ++c;
      }
    }
    __syncthreads();
    if (threadIdx.x == 0)
      __hip_atomic_store(gx, epoch, __ATOMIC_RELAXED, __HIP_MEMORY_SCOPE_AGENT);
  } else {
    if (threadIdx.x == 0){
      __hip_atomic_store(&fx[rank * FPAD], epoch, __ATOMIC_RELAXED, __HIP_MEMORY_SCOPE_AGENT);
      int c = 0;
      while (__hip_atomic_load(gx, __ATOMIC_RELAXED, __HIP_MEMORY_SCOPE_AGENT) < epoch && c < SPIN_CAP){
        __builtin_amdgcn_s_sleep(2); ++c;
      }
    }
    __syncthreads();
  }
  asm volatile("" ::: "memory");
}

// ---------------- convert / transpose helpers ----------------

__global__ void cvt_vec4(const float4* __restrict__ x, ushort4* __restrict__ y, int n4){
  int i = blockIdx.x * 256 + threadIdx.x;
  if (i < n4){
    float4 v = x[i];
    ushort4 o;
    o.x = f2bf(v.x); o.y = f2bf(v.y); o.z = f2bf(v.z); o.w = f2bf(v.w);
    y[i] = o;
  }
}

__global__ void transpose_cvt(const float* __restrict__ src, unsigned short* __restrict__ dstT,
                              int CS, int DS, int koff){
  __shared__ float tile[32][33];
  int c0 = blockIdx.x * 32, r0 = blockIdx.y * 32;
  int tx = threadIdx.x, ty = threadIdx.y;
  for (int i = ty; i < 32; i += 8) tile[i][tx] = src[(size_t)(r0 + i) * CS + c0 + tx];
  __syncthreads();
  for (int i = ty; i < 32; i += 8)
    dstT[(size_t)(c0 + i) * DS + koff + r0 + tx] = f2bf(tile[tx][i]);
}

// ---------------- control precompute ----------------
// Adds: per-slot child wait-indices (node-flag idx if child is a tail node,
// else -1), per-XCD tailStart, root wait idx, node-flag zeroing.
__global__ void precompute_ctrl(const int* __restrict__ trans,
                                int* __restrict__ srcL, int* __restrict__ srcR,
                                int* __restrict__ srcLW, int* __restrict__ srcRW,
                                int* __restrict__ dstv, int* __restrict__ cnt,
                                int* __restrict__ outsrc, int* __restrict__ rootW,
                                int* __restrict__ nf, int* __restrict__ bar){
  __shared__ int stk[Bn][Ln + 1];
  __shared__ int scnt[NXCD * NLVL];
  __shared__ int smaxl[NXCD];
  __shared__ int stail[NXCD];
  int b = threadIdx.x;
  for (int i = b; i < NXCD * NLVL; i += 128) scnt[i] = 0;
  if (b < NXCD) smaxl[b] = 0;
  for (int i = b; i < BAR_INTS; i += 128) bar[i] = 0;
  for (int i = b; i < NODE_ROWS; i += 128) nf[i] = 0;
  __syncthreads();
  int x = b & 7;
  int sp = 0, bp = 0, nodecnt = 0;
  int act_next = trans[b * Tn];
  for (int t = 0; t < Tn; t++){
    int act = act_next;
    if (t + 1 < Tn) act_next = trans[b * Tn + t + 1];
    int ops = Tn - t;
    if (sp > ops) act = 2;                       // forced REDUCE (matches ref)
    if (act == 2){
      int R = stk[b][sp - 1], L = stk[b][sp - 2];
      int lvl = max(R >> 20, L >> 20) + 1;
      int slot = atomicAdd(&scnt[x * NLVL + lvl], 1);
      int base = (x * NLVL + lvl) * CAPX + slot;
      srcL[base] = (L & 0xFFFFF) * Hn;
      srcR[base] = (R & 0xFFFFF) * Hn;
      srcLW[base] = L >> 20;                     // temp: child level
      srcRW[base] = R >> 20;
      int noderow = LEAF_ROWS + b * (Ln - 1) + nodecnt;
      dstv[base] = noderow * Hn;
      stk[b][sp - 2] = noderow | (lvl << 20);
      sp -= 1; nodecnt++;
    } else {
      stk[b][sp] = b * Ln + min(bp, Ln - 1);
      sp += 1; bp += 1;
    }
  }
  int root = stk[b][max(sp - 1, 0)];
  outsrc[b] = (root & 0xFFFFF) * Hn;
  atomicMax(&smaxl[x], root >> 20);
  __syncthreads();
  if (b < NXCD){
    int ts = NLVL;
    for (int l = 1; l < NLVL; l++){
      if (scnt[b * NLVL + l] < 128){ ts = l; break; }
    }
    stail[b] = max(ts, 2);
  }
  __syncthreads();
  // pass 2: convert child levels -> wait indices
  for (int p = b; p < NXCD * NLVL; p += 128){
    int px = p / NLVL, lvl = p - px * NLVL;
    int n = scnt[p], ts = stail[px];
    for (int s = 0; s < n; s++){
      int idx = p * CAPX + s;
      int ll = srcLW[idx], rl = srcRW[idx];
      srcLW[idx] = (lvl >= ts && ll >= ts) ? ((srcL[idx] >> 9) - LEAF_ROWS) : -1;
      srcRW[idx] = (lvl >= ts && rl >= ts) ? ((srcR[idx] >> 9) - LEAF_ROWS) : -1;
    }
  }
  int rlvl = root >> 20;
  rootW[b] = (rlvl >= stail[x]) ? ((root & 0xFFFFF) - LEAF_ROWS) : -1;
  __syncthreads();
  for (int i = b; i < NXCD * NLVL; i += 128) cnt[i] = scnt[i];
  if (b < NXCD){
    cnt[NXCD * NLVL + b] = smaxl[b];
    cnt[NXCD * NLVL + NXCD + b] = stail[b];
  }
}

// ---------------- word GEMM (PF1; M-tile fast-varying -> XCD M-affinity) ----------------
__global__ __launch_bounds__(256) void word_gemm(
    const unsigned short* __restrict__ SB, const unsigned short* __restrict__ WwT,
    const float* __restrict__ b_word,
    unsigned short* __restrict__ HB, float* __restrict__ CF){
  int mt = blockIdx.x;            // 128 M-tiles (fast-varying -> XCD-affine)
  int nt = blockIdx.y;            // 8 N-tiles
  int tid = threadIdx.x, w = tid >> 6, lane = tid & 63;
  int wm = w >> 1, wn = w & 1;
  int rc = lane & 15, lg = lane >> 4;
  const unsigned short* ap0 = SB + (size_t)(mt * 64 + wm * 32 + rc) * En + lg * 8;
  const unsigned short* ap1 = ap0 + (size_t)16 * En;
  const unsigned short* bp0 = WwT + (size_t)(nt * 128 + wn * 64 + rc) * En + lg * 8;
  f32x4 acc[2][4];
  #pragma unroll
  for (int h = 0; h < 2; h++)
    #pragma unroll
    for (int nb = 0; nb < 4; nb++) acc[h][nb] = (f32x4){0.f,0.f,0.f,0.f};

  bf16x8 a0c = *(const bf16x8*)ap0;
  bf16x8 a1c = *(const bf16x8*)ap1;
  bf16x8 bc[4];
  #pragma unroll
  for (int nb = 0; nb < 4; nb++) bc[nb] = *(const bf16x8*)(bp0 + (size_t)nb * 16 * En);

  #pragma unroll
  for (int j = 0; j < 16; ++j){
    bf16x8 a0n, a1n, bn[4];
    if (j < 15){
      int kn = (j + 1) * 32;
      a0n = *(const bf16x8*)(ap0 + kn);
      a1n = *(const bf16x8*)(ap1 + kn);
      #pragma unroll
      for (int nb = 0; nb < 4; nb++)
        bn[nb] = *(const bf16x8*)(bp0 + (size_t)nb * 16 * En + kn);
    }
    #pragma unroll
    for (int nb = 0; nb < 4; nb++){
      acc[0][nb] = __builtin_amdgcn_mfma_f32_16x16x32_bf16(a0c, bc[nb], acc[0][nb], 0, 0, 0);
      acc[1][nb] = __builtin_amdgcn_mfma_f32_16x16x32_bf16(a1c, bc[nb], acc[1][nb], 0, 0, 0);
    }
    a0c = a0n; a1c = a1n;
    #pragma unroll
    for (int nb = 0; nb < 4; nb++) bc[nb] = bn[nb];
  }
  #pragma unroll
  for (int nb = 0; nb < 4; nb++){
    int col = nt * 128 + wn * 64 + nb * 16 + rc;
    float bw = b_word[col];
    #pragma unroll
    for (int h = 0; h < 2; h++){
      #pragma unroll
      for (int q = 0; q < 4; q++){
        int row = mt * 64 + wm * 32 + h * 16 + lg * 4 + q;
        float v = acc[h][nb][q] + bw;
        if (col < Hn) HB[(size_t)row * Hn + col] = f2bf(v);
        else          CF[(size_t)row * Hn + (col - Hn)] = v;
      }
    }
  }
}

// ---------------- big-level tile: 64 rows x 16 u, full K per wave (r12 form) ----------------
template<bool LDSB>
static __device__ __forceinline__ void tile64(
    int u0, int t, int nr, const int* __restrict__ sL, const int* __restrict__ sR,
    const int* __restrict__ dl,
    unsigned short* __restrict__ HB, float* __restrict__ CF,
    const unsigned short* __restrict__ WT, const float* __restrict__ b_red,
    const unsigned short* __restrict__ wlds, int rc, int lg)
{
  int base = t * 64;
  int offL[4], offR[4];
  #pragma unroll
  for (int m = 0; m < 4; m++){
    int i = min(base + m * 16 + rc, nr - 1);
    offL[m] = sL[i]; offR[m] = sR[i];
  }
  f32x4 acc[5][4];
  #pragma unroll
  for (int g = 0; g < 5; g++)
    #pragma unroll
    for (int m = 0; m < 4; m++) acc[g][m] = (f32x4){0.f,0.f,0.f,0.f};

  int bswz = (rc & 7) << 3;
  const unsigned short* gb = WT + (size_t)(u0 + rc) * 1024 + lg * 8;

  bf16x8 a_cur[4], b_cur[3];
  #pragma unroll
  for (int m = 0; m < 4; m++) a_cur[m] = *(const bf16x8*)(HB + offL[m] + lg * 8);
  #pragma unroll
  for (int g = 0; g < 3; g++)
    b_cur[g] = *(const bf16x8*)(gb + (size_t)(g + 2) * GATE_STRIDE);

  #pragma unroll 4
  for (int j = 0; j < 32; ++j){
    bf16x8 a_nxt[4], b_nxt[3];
    if (j < 31){
      int kn = (j + 1) * 32 + lg * 8;
      #pragma unroll
      for (int m = 0; m < 4; m++){
        const unsigned short* ap = (j + 1 < 16) ? (HB + offL[m] + kn) : (HB + offR[m] + (kn - 512));
        a_nxt[m] = *(const bf16x8*)ap;
      }
      #pragma unroll
      for (int g = 0; g < 3; g++)
        b_nxt[g] = *(const bf16x8*)(gb + (size_t)(g + 2) * GATE_STRIDE + (j + 1) * 32);
    }
    int k = j * 32 + lg * 8;
    #pragma unroll
    for (int g = 0; g < 2; g++){
      bf16x8 bb;
      if (LDSB) bb = *(const bf16x8*)&wlds[(size_t)(g * 16 + rc) * 1024 + (k ^ bswz)];
      else      bb = *(const bf16x8*)(gb + (size_t)g * GATE_STRIDE + j * 32);
      #pragma unroll
      for (int m = 0; m < 4; m++)
        acc[g][m] = __builtin_amdgcn_mfma_f32_16x16x32_bf16(a_cur[m], bb, acc[g][m], 0, 0, 0);
    }
    #pragma unroll
    for (int g = 0; g < 3; g++){
      #pragma unroll
      for (int m = 0; m < 4; m++)
        acc[g + 2][m] = __builtin_amdgcn_mfma_f32_16x16x32_bf16(a_cur[m], b_cur[g], acc[g + 2][m], 0, 0, 0);
    }
    #pragma unroll
    for (int m = 0; m < 4; m++) a_cur[m] = a_nxt[m];
    #pragma unroll
    for (int g = 0; g < 3; g++) b_cur[g] = b_nxt[g];
  }
  int colu = u0 + rc;
  float bs[5];
  #pragma unroll
  for (int g = 0; g < 5; g++) bs[g] = b_red[g * Hn + colu];
  #pragma unroll
  for (int m = 0; m < 4; m++){
    #pragma unroll
    for (int q = 0; q < 4; q++){
      int i = base + m * 16 + lg * 4 + q;
      if (i < nr){
        int oL = sL[i], oR = sR[i], oD = dl[i];
        float gv = tanh_fast(acc[0][m][q] + bs[0]);
        float iv = sigm(acc[1][m][q] + bs[1]);
        float f1 = sigm(acc[2][m][q] + bs[2]);
        float f2 = sigm(acc[3][m][q] + bs[3]);
        float ov = sigm(acc[4][m][q] + bs[4]);
        float cl = __builtin_nontemporal_load(CF + oL + colu);
        float cr = __builtin_nontemporal_load(CF + oR + colu);
        float cv = gv * iv + f1 * cl + f2 * cr;
        float hv = ov * tanh_fast(cv);
        __builtin_nontemporal_store(cv, CF + oD + colu);
        HB[oD + colu] = f2bf(hv);
      }
    }
  }
}

// ---------------- small-level tile: 16 rows x 16 u, K split over 4 waves ----------------
// FLAGS: consumer spins on its rows' child node-flags (==32) before loading;
// producer atomicAdds its 16 node flags after the vmcnt-drained final barrier.
template<bool FLAGS>
static __device__ __forceinline__ void tile16(
    int u0, int t, int nr, const int* __restrict__ sL, const int* __restrict__ sR,
    const int* __restrict__ dl,
    const int* __restrict__ sLW, const int* __restrict__ sRW, int* __restrict__ nf,
    unsigned short* __restrict__ HB, float* __restrict__ CF,
    const unsigned short* __restrict__ WT, const float* __restrict__ b_red,
    const unsigned short* __restrict__ wlds, float (*part)[2][16][20],
    int tid, int w, int rc, int lg)
{
  int base = t * 16;
  int er = tid >> 4, eu = tid & 15;
  if (FLAGS){
    int rr = min(base + (tid & 15), nr - 1);
    int wl = sLW[rr], wr = sRW[rr];
    int c = 0;
    if (wl >= 0){
      while (__hip_atomic_load(&nf[wl], __ATOMIC_RELAXED, __HIP_MEMORY_SCOPE_AGENT) < 32 && c < WSPIN){
        __builtin_amdgcn_s_sleep(1); ++c;
      }
    }
    c = 0;
    if (wr >= 0){
      while (__hip_atomic_load(&nf[wr], __ATOMIC_RELAXED, __HIP_MEMORY_SCOPE_AGENT) < 32 && c < WSPIN){
        __builtin_amdgcn_s_sleep(1); ++c;
      }
    }
  }
  int i0 = min(base + rc, nr - 1);
  int offA = (w >= 2) ? sR[i0] : sL[i0];
  int ie = min(base + er, nr - 1);
  int oL = sL[ie], oR = sR[ie], oD = dl[ie];
  int colu = u0 + eu;
  float cl = __builtin_nontemporal_load(CF + oL + colu);
  float cr = __builtin_nontemporal_load(CF + oR + colu);

  int k0 = w * 256;                       // this wave's K quarter (of 1024)
  int abase = (w >= 2) ? (k0 - 512) : k0; // child-local K offset
  const unsigned short* ap = HB + offA + abase + lg * 8;
  int bswz = (rc & 7) << 3;
  const unsigned short* gb = WT + (size_t)(u0 + rc) * 1024;

  f32x4 acc[5];
  #pragma unroll
  for (int g = 0; g < 5; g++) acc[g] = (f32x4){0.f,0.f,0.f,0.f};

  bf16x8 a_cur = *(const bf16x8*)ap;
  bf16x8 b_cur[3];
  #pragma unroll
  for (int g = 0; g < 3; g++)
    b_cur[g] = *(const bf16x8*)(gb + (size_t)(g + 2) * GATE_STRIDE + k0 + lg * 8);

  #pragma unroll
  for (int j = 0; j < 8; ++j){
    bf16x8 a_nxt, b_nxt[3];
    if (j < 7){
      a_nxt = *(const bf16x8*)(ap + (j + 1) * 32);
      #pragma unroll
      for (int g = 0; g < 3; g++)
        b_nxt[g] = *(const bf16x8*)(gb + (size_t)(g + 2) * GATE_STRIDE + k0 + (j + 1) * 32 + lg * 8);
    }
    int k = k0 + j * 32 + lg * 8;
    #pragma unroll
    for (int g = 0; g < 2; g++){
      bf16x8 bb = *(const bf16x8*)&wlds[(size_t)(g * 16 + rc) * 1024 + (k ^ bswz)];
      acc[g] = __builtin_amdgcn_mfma_f32_16x16x32_bf16(a_cur, bb, acc[g], 0, 0, 0);
    }
    #pragma unroll
    for (int g = 0; g < 3; g++)
      acc[g + 2] = __builtin_amdgcn_mfma_f32_16x16x32_bf16(a_cur, b_cur[g], acc[g + 2], 0, 0, 0);
    a_cur = a_nxt;
    #pragma unroll
    for (int g = 0; g < 3; g++) b_cur[g] = b_nxt[g];
  }
  // combine across waves, gate pairs (LDS [4][2][16][20])
  float sg[5];
  #pragma unroll
  for (int r = 0; r < 3; ++r){
    int ng = (r < 2) ? 2 : 1;
    #pragma unroll
    for (int gi = 0; gi < 2; ++gi){
      if (gi < ng){
        int g = r * 2 + gi;
        #pragma unroll
        for (int q = 0; q < 4; q++) part[w][gi][lg * 4 + q][rc] = acc[g][q];
      }
    }
    __syncthreads();
    #pragma unroll
    for (int gi = 0; gi < 2; ++gi){
      if (gi < ng)
        sg[r * 2 + gi] = part[0][gi][er][eu] + part[1][gi][er][eu]
                       + part[2][gi][er][eu] + part[3][gi][er][eu];
    }
    __syncthreads();
  }
  int i = base + er;
  if (i < nr){
    float gv = tanh_fast(sg[0] + b_red[colu]);
    float iv = sigm(sg[1] + b_red[Hn + colu]);
    float f1 = sigm(sg[2] + b_red[2 * Hn + colu]);
    float f2 = sigm(sg[3] + b_red[3 * Hn + colu]);
    float ov = sigm(sg[4] + b_red[4 * Hn + colu]);
    float cv = gv * iv + f1 * cl + f2 * cr;
    float hv = ov * tanh_fast(cv);
    __builtin_nontemporal_store(cv, CF + oD + colu);
    HB[oD + colu] = f2bf(hv);
  }
  __syncthreads();   // drains vmcnt: stores globally visible before flags
  if (FLAGS){
    if (tid < 16 && base + tid < nr)
      __hip_atomic_fetch_add(&nf[(dl[base + tid] >> 9) - LEAF_ROWS], 1,
                             __ATOMIC_RELAXED, __HIP_MEMORY_SCOPE_AGENT);
  }
}

// ---------------- persistent XCD-sharded tree kernel ----------------
extern __shared__ char dynbuf[];

__global__ __launch_bounds__(256, 2) void tree_kernel(
    unsigned short* __restrict__ HB, float* __restrict__ CF,
    const unsigned short* __restrict__ WT, const float* __restrict__ b_red,
    const int* __restrict__ srcL, const int* __restrict__ srcR,
    const int* __restrict__ srcLW, const int* __restrict__ srcRW,
    const int* __restrict__ dstv, const int* __restrict__ cnt,
    const int* __restrict__ outsrc, const int* __restrict__ rootW,
    int* __restrict__ nf, float* __restrict__ out, int* bar){
  unsigned short* wlds = (unsigned short*)dynbuf;             // 64KB: gates 0-1
  float (*part)[2][16][20] = (float(*)[2][16][20])(dynbuf + WLDS_BYTES);
  int bid = blockIdx.x;
  int tid = threadIdx.x, w = tid >> 6, lane = tid & 63;
  int rc = lane & 15, lg = lane >> 4;

  int x = xcc_id();
  if (tid == 0){
    int r = __hip_atomic_fetch_add(&bar[OFF_CENSUS + x * FPAD], 1,
                                   __ATOMIC_RELAXED, __HIP_MEMORY_SCOPE_AGENT);
    __hip_atomic_store(&bar[OFF_RANK + bid * FPAD], r, __ATOMIC_RELAXED, __HIP_MEMORY_SCOPE_AGENT);
  }
  __syncthreads();
  int rank = min(__hip_atomic_load(&bar[OFF_RANK + bid * FPAD], __ATOMIC_RELAXED, __HIP_MEMORY_SCOPE_AGENT),
                 MAXRANK - 1);
  int ub = rank & 31;
  int u0 = ub * 16;

  // stage gates 0-1 of this u-block into LDS (XOR-swizzled k)
  for (int gg = tid; gg < 4096; gg += 256){
    int row = gg >> 7;                 // g*16 + u, 0..31
    int k = (gg & 127) * 8;
    int u = row & 15, g = row >> 4;
    bf16x8 v = *(const bf16x8*)(WT + (size_t)(g * 512 + u0 + u) * 1024 + k);
    int kx = k ^ ((u & 7) << 3);
    *(bf16x8*)&wlds[(size_t)row * 1024 + kx] = v;
  }
  __syncthreads();

  // global start barrier so census counts are final
  {
    int* sfl  = bar + OFF_SFLAG;
    int* sgen = bar + OFF_SGEN;
    if (bid == 0){
      for (int i = tid; i < NBLK; i += 256){
        if (i){
          int c = 0;
          while (__hip_atomic_load(&sfl[i * FPAD], __ATOMIC_RELAXED, __HIP_MEMORY_SCOPE_AGENT) == 0 && c < SPIN_CAP){
            __builtin_amdgcn_s_sleep(1); ++c;
          }
        }
      }
      __syncthreads();
      if (tid == 0) __hip_atomic_store(sgen, 1, __ATOMIC_RELAXED, __HIP_MEMORY_SCOPE_AGENT);
    } else {
      if (tid == 0){
        __hip_atomic_store(&sfl[bid * FPAD], 1, __ATOMIC_RELAXED, __HIP_MEMORY_SCOPE_AGENT);
        int c = 0;
        while (__hip_atomic_load(sgen, __ATOMIC_RELAXED, __HIP_MEMORY_SCOPE_AGENT) == 0 && c < SPIN_CAP){
          __builtin_amdgcn_s_sleep(2); ++c;
        }
      }
      __syncthreads();
    }
  }
  int nx = max(__hip_atomic_load(&bar[OFF_CENSUS + x * FPAD], __ATOMIC_RELAXED, __HIP_MEMORY_SCOPE_AGENT), 1);

  int maxlvl   = cnt[NXCD * NLVL + x];
  int tailStart = cnt[NXCD * NLVL + NXCD + x];
  bool flagmode = (nx >= 32);
  int epoch = 1;
  for (int lvl = 1; lvl <= maxlvl; ++lvl){
    int nr = cnt[x * NLVL + lvl];
    const int* sL  = srcL  + (x * NLVL + lvl) * CAPX;
    const int* sR  = srcR  + (x * NLVL + lvl) * CAPX;
    const int* sLW = srcLW + (x * NLVL + lvl) * CAPX;
    const int* sRW = srcRW + (x * NLVL + lvl) * CAPX;
    const int* dl  = dstv  + (x * NLVL + lvl) * CAPX;
    bool tailmode = flagmode && (lvl >= tailStart);
    if (nr > 0){
      if (tailmode){
        int nstr = (nx - 1 - ub) / 32 + 1;
        int stripe = rank >> 5;
        int ntl16 = (nr + 15) >> 4;
        for (int t = stripe; t < ntl16; t += nstr)
          tile16<true>(u0, t, nr, sL, sR, dl, sLW, sRW, nf, HB, CF, WT, b_red, wlds, part, tid, w, rc, lg);
      } else if (flagmode){
        int nstr = (nx - 1 - ub) / 32 + 1;
        int stripe = rank >> 5;
        if (nr >= 128){
          int ntl = (nr + 63) >> 6;
          for (int t = stripe * 4 + w; t < ntl; t += nstr * 4)
            tile64<true>(u0, t, nr, sL, sR, dl, HB, CF, WT, b_red, wlds, rc, lg);
        } else {
          int ntl16 = (nr + 15) >> 4;
          for (int t = stripe; t < ntl16; t += nstr)
            tile16<false>(u0, t, nr, sL, sR, dl, sLW, sRW, nf, HB, CF, WT, b_red, wlds, part, tid, w, rc, lg);
        }
      } else {
        // rare fallback: cover all 32 u-blocks from global, barrier every level
        int ntl = (nr + 63) >> 6;
        int nwv = nx * 4, wid = rank * 4 + w;
        int ntask = ntl * 32;
        for (int task = wid; task < ntask; task += nwv)
          tile64<false>((task / ntl) * 16, task % ntl, nr, sL, sR, dl, HB, CF, WT, b_red, wlds, rc, lg);
      }
    }
    if (!tailmode){
      xcd_barrier(bar, x, rank, nx, epoch);
      ++epoch;
    }
  }

  // final gather for this XCD's 16 trees (wait tail roots via flags)
  for (int j = rank; j < 16; j += min(nx, MAXRANK)){
    int b = x + 8 * j;
    if (flagmode){
      int rw = rootW[b];
      if (rw >= 0){
        int c = 0;
        while (__hip_atomic_load(&nf[rw], __ATOMIC_RELAXED, __HIP_MEMORY_SCOPE_AGENT) < 32 && c < WSPIN){
          __builtin_amdgcn_s_sleep(1); ++c;
        }
      }
    }
    int src = outsrc[b];
    out[b * Hn + tid]       = bf2f(HB[src + tid]);
    out[b * Hn + tid + 256] = bf2f(HB[src + tid + 256]);
  }
}

// ---------------- launch ----------------
extern "C" void kernel_launch(void* const* d_in, const int* in_sizes, int n_in,
                              void* d_out, int out_size, void* d_ws, size_t ws_size,
                              hipStream_t stream){
  (void)in_sizes; (void)n_in; (void)out_size; (void)ws_size;
  const float* sentence = (const float*)d_in[0];
  const int*   trans    = (const int*)d_in[1];
  const float* W_word   = (const float*)d_in[2];
  const float* b_word   = (const float*)d_in[3];
  const float* W_left   = (const float*)d_in[4];
  const float* W_right  = (const float*)d_in[5];
  const float* b_red    = (const float*)d_in[6];

  char* ws = (char*)d_ws;
  size_t off = 0;
  auto alloc = [&](size_t bytes) -> void* {
    void* p = ws + off;
    off += (bytes + 255) & ~((size_t)255);
    return p;
  };
  unsigned short* HB  = (unsigned short*)alloc((size_t)TOT_ROWS * Hn * 2);
  float*          CF  = (float*)alloc((size_t)TOT_ROWS * Hn * 4);
  unsigned short* WT  = (unsigned short*)alloc((size_t)2560 * 1024 * 2);
  unsigned short* SB  = (unsigned short*)alloc((size_t)LEAF_ROWS * En * 2);
  unsigned short* WwT = (unsigned short*)alloc((size_t)1024 * En * 2);
  int* srcL   = (int*)alloc((size_t)NXCD * NLVL * CAPX * 4);
  int* srcR   = (int*)alloc((size_t)NXCD * NLVL * CAPX * 4);
  int* srcLW  = (int*)alloc((size_t)NXCD * NLVL * CAPX * 4);
  int* srcRW  = (int*)alloc((size_t)NXCD * NLVL * CAPX * 4);
  int* dstv   = (int*)alloc((size_t)NXCD * NLVL * CAPX * 4);
  int* cnt    = (int*)alloc((size_t)(NXCD * NLVL + 2 * NXCD) * 4);
  int* outsrc = (int*)alloc((size_t)Bn * 4);
  int* rootW  = (int*)alloc((size_t)Bn * 4);
  int* nf     = (int*)alloc((size_t)NODE_ROWS * 4);
  int* bar    = (int*)alloc((size_t)BAR_INTS * 4);
  float* outp = (float*)d_out;

  hipFuncSetAttribute(reinterpret_cast<const void*>(tree_kernel),
                      hipFuncAttributeMaxDynamicSharedMemorySize, DYN_BYTES);

  cvt_vec4<<<(LEAF_ROWS * En / 4) / 256, 256, 0, stream>>>((const float4*)sentence, (ushort4*)SB, LEAF_ROWS * En / 4);
  transpose_cvt<<<dim3(1024 / 32, En / 32), dim3(32, 8), 0, stream>>>(W_word, WwT, 1024, En, 0);
  transpose_cvt<<<dim3(2560 / 32, Hn / 32), dim3(32, 8), 0, stream>>>(W_left, WT, 2560, 1024, 0);
  transpose_cvt<<<dim3(2560 / 32, Hn / 32), dim3(32, 8), 0, stream>>>(W_right, WT, 2560, 1024, 512);
  precompute_ctrl<<<1, 128, 0, stream>>>(trans, srcL, srcR, srcLW, srcRW, dstv, cnt, outsrc, rootW, nf, bar);
  word_gemm<<<dim3(128, 8), 256, 0, stream>>>(SB, WwT, b_word, HB, CF);
  tree_kernel<<<NBLK, 256, DYN_BYTES, stream>>>(HB, CF, WT, b_red, srcL, srcR, srcLW, srcRW,
                                                dstv, cnt, outsrc, rootW, nf, outp, bar);
}

// Round 17
// 726.107 us; speedup vs baseline: 1.1901x; 1.1901x over previous
//
#include <hip/hip_runtime.h>
#include <hip/hip_bf16.h>

// SPINN: word GEMM + XCD-sharded persistent TreeLSTM.
// r17: r15 base + (1) tile16 FULL A/B preload (all 8 A + 24 B frags upfront;
// waves_per_eu(2,2) => 256-VGPR cap, no spill, same 2 blocks/CU), (2) all-to-all
// barrier (1 fabric hop instead of 2), (3) pre-barrier index preload + 4-sync
// combine. r16's per-node flags reverted (32-producer fan-in = barrier anyway).
// B=128, L=64, E=512, H=512, T=127.

#define Bn 128
#define Ln 64
#define En 512
#define Hn 512
#define Tn 127
#define LEAF_ROWS (Bn*Ln)
#define NODE_ROWS (Bn*(Ln-1))
#define TOT_ROWS (LEAF_ROWS+NODE_ROWS)
#define NLVL 64
#define NXCD 8
#define CAPX 512                 // max rows per XCD-bin per level
#define NBLK 512                 // 2 blocks/CU
#define FPAD 16
#define MAXRANK 96
#define SPIN_CAP (1<<22)
#define GATE_STRIDE (512*1024)
#define WLDS_BYTES 65536         // 2 gates x 16u x 1024k x 2B
#define PART_BYTES (4*3*16*20*4) // [wave][gate-slot(3)][row][col+pad] f32
#define DYN_BYTES (WLDS_BYTES + PART_BYTES)   // 80896 B -> 2 blocks/CU in 160KB

// barrier/census state layout (ints), zeroed by precompute_ctrl each call
#define OFF_CENSUS 0                              // NXCD*FPAD
#define OFF_RANK   (OFF_CENSUS + NXCD*FPAD)       // NBLK*FPAD
#define OFF_SFLAG  (OFF_RANK + NBLK*FPAD)         // NBLK*FPAD
#define OFF_SGEN   (OFF_SFLAG + NBLK*FPAD)        // FPAD
#define OFF_FX     (OFF_SGEN + FPAD)              // NXCD*MAXRANK*FPAD
#define BAR_INTS   (OFF_FX + NXCD*MAXRANK*FPAD)

typedef __attribute__((ext_vector_type(8))) short bf16x8;
typedef __attribute__((ext_vector_type(4))) float f32x4;

static __device__ __forceinline__ float bf2f(unsigned short u){
  unsigned v = ((unsigned)u) << 16;
  float f; __builtin_memcpy(&f, &v, 4); return f;
}
static __device__ __forceinline__ unsigned short f2bf(float f){
  unsigned u; __builtin_memcpy(&u, &f, 4);
  u = u + 0x7FFFu + ((u >> 16) & 1u);   // round-nearest-even
  return (unsigned short)(u >> 16);
}
static __device__ __forceinline__ float sigm(float x){
  return 1.0f / (1.0f + __expf(-x));
}
static __device__ __forceinline__ float tanh_fast(float x){
  x = fminf(fmaxf(x, -15.0f), 15.0f);
  float t = __expf(2.0f * x);
  return (t - 1.0f) / (t + 1.0f);
}
static __device__ __forceinline__ int xcc_id(){
  unsigned v;
  asm volatile("s_getreg_b32 %0, hwreg(HW_REG_XCC_ID)" : "=s"(v));
  return (int)(v & 7);
}

// All-to-all per-XCD barrier: every block stores its arrival flag; every block's
// lane i polls flag i. One fabric hop (arrive -> observed) instead of two.
static __device__ __forceinline__ void xcd_barrier(int* bar, int x, int rank, int nx, int epoch){
  __syncthreads();
  int* fx = bar + OFF_FX + x * MAXRANK * FPAD;
  if (threadIdx.x == 0)
    __hip_atomic_store(&fx[rank * FPAD], epoch, __ATOMIC_RELAXED, __HIP_MEMORY_SCOPE_AGENT);
  int nxl = min(nx, MAXRANK);
  if ((int)threadIdx.x < nxl){
    int c = 0;
    while (__hip_atomic_load(&fx[threadIdx.x * FPAD], __ATOMIC_RELAXED, __HIP_MEMORY_SCOPE_AGENT) < epoch
           && c < SPIN_CAP){
      if (c > 8) __builtin_amdgcn_s_sleep(1);
      ++c;
    }
  }
  __syncthreads();
  asm volatile("" ::: "memory");
}

// ---------------- convert / transpose helpers ----------------

__global__ void cvt_vec4(const float4* __restrict__ x, ushort4* __restrict__ y, int n4){
  int i = blockIdx.x * 256 + threadIdx.x;
  if (i < n4){
    float4 v = x[i];
    ushort4 o;
    o.x = f2bf(v.x); o.y = f2bf(v.y); o.z = f2bf(v.z); o.w = f2bf(v.w);
    y[i] = o;
  }
}

__global__ void transpose_cvt(const float* __restrict__ src, unsigned short* __restrict__ dstT,
                              int CS, int DS, int koff){
  __shared__ float tile[32][33];
  int c0 = blockIdx.x * 32, r0 = blockIdx.y * 32;
  int tx = threadIdx.x, ty = threadIdx.y;
  for (int i = ty; i < 32; i += 8) tile[i][tx] = src[(size_t)(r0 + i) * CS + c0 + tx];
  __syncthreads();
  for (int i = ty; i < 32; i += 8)
    dstT[(size_t)(c0 + i) * DS + koff + r0 + tx] = f2bf(tile[tx][i]);
}

// ---------------- control precompute (r15 form) ----------------
__global__ void precompute_ctrl(const int* __restrict__ trans,
                                int* __restrict__ srcL, int* __restrict__ srcR,
                                int* __restrict__ dstv, int* __restrict__ cnt,
                                int* __restrict__ outsrc, int* __restrict__ bar){
  __shared__ int stk[Bn][Ln + 1];
  __shared__ int scnt[NXCD * NLVL];
  __shared__ int smaxl[NXCD];
  int b = threadIdx.x;
  for (int i = b; i < NXCD * NLVL; i += 128) scnt[i] = 0;
  if (b < NXCD) smaxl[b] = 0;
  for (int i = b; i < BAR_INTS; i += 128) bar[i] = 0;
  __syncthreads();
  int x = b & 7;
  int sp = 0, bp = 0, nodecnt = 0;
  int act_next = trans[b * Tn];
  for (int t = 0; t < Tn; t++){
    int act = act_next;
    if (t + 1 < Tn) act_next = trans[b * Tn + t + 1];
    int ops = Tn - t;
    if (sp > ops) act = 2;                       // forced REDUCE (matches ref)
    if (act == 2){
      int R = stk[b][sp - 1], L = stk[b][sp - 2];
      int lvl = max(R >> 20, L >> 20) + 1;
      int slot = atomicAdd(&scnt[x * NLVL + lvl], 1);
      int base = (x * NLVL + lvl) * CAPX + slot;
      srcL[base] = (L & 0xFFFFF) * Hn;
      srcR[base] = (R & 0xFFFFF) * Hn;
      int noderow = LEAF_ROWS + b * (Ln - 1) + nodecnt;
      dstv[base] = noderow * Hn;
      stk[b][sp - 2] = noderow | (lvl << 20);
      sp -= 1; nodecnt++;
    } else {
      stk[b][sp] = b * Ln + min(bp, Ln - 1);
      sp += 1; bp += 1;
    }
  }
  int root = stk[b][max(sp - 1, 0)];
  outsrc[b] = (root & 0xFFFFF) * Hn;
  atomicMax(&smaxl[x], root >> 20);
  __syncthreads();
  for (int i = b; i < NXCD * NLVL; i += 128) cnt[i] = scnt[i];
  if (b < NXCD) cnt[NXCD * NLVL + b] = smaxl[b];
}

// ---------------- word GEMM (PF1; M-tile fast-varying -> XCD M-affinity) ----------------
__global__ __launch_bounds__(256) void word_gemm(
    const unsigned short* __restrict__ SB, const unsigned short* __restrict__ WwT,
    const float* __restrict__ b_word,
    unsigned short* __restrict__ HB, float* __restrict__ CF){
  int mt = blockIdx.x;            // 128 M-tiles (fast-varying -> XCD-affine)
  int nt = blockIdx.y;            // 8 N-tiles
  int tid = threadIdx.x, w = tid >> 6, lane = tid & 63;
  int wm = w >> 1, wn = w & 1;
  int rc = lane & 15, lg = lane >> 4;
  const unsigned short* ap0 = SB + (size_t)(mt * 64 + wm * 32 + rc) * En + lg * 8;
  const unsigned short* ap1 = ap0 + (size_t)16 * En;
  const unsigned short* bp0 = WwT + (size_t)(nt * 128 + wn * 64 + rc) * En + lg * 8;
  f32x4 acc[2][4];
  #pragma unroll
  for (int h = 0; h < 2; h++)
    #pragma unroll
    for (int nb = 0; nb < 4; nb++) acc[h][nb] = (f32x4){0.f,0.f,0.f,0.f};

  bf16x8 a0c = *(const bf16x8*)ap0;
  bf16x8 a1c = *(const bf16x8*)ap1;
  bf16x8 bc[4];
  #pragma unroll
  for (int nb = 0; nb < 4; nb++) bc[nb] = *(const bf16x8*)(bp0 + (size_t)nb * 16 * En);

  #pragma unroll
  for (int j = 0; j < 16; ++j){
    bf16x8 a0n, a1n, bn[4];
    if (j < 15){
      int kn = (j + 1) * 32;
      a0n = *(const bf16x8*)(ap0 + kn);
      a1n = *(const bf16x8*)(ap1 + kn);
      #pragma unroll
      for (int nb = 0; nb < 4; nb++)
        bn[nb] = *(const bf16x8*)(bp0 + (size_t)nb * 16 * En + kn);
    }
    #pragma unroll
    for (int nb = 0; nb < 4; nb++){
      acc[0][nb] = __builtin_amdgcn_mfma_f32_16x16x32_bf16(a0c, bc[nb], acc[0][nb], 0, 0, 0);
      acc[1][nb] = __builtin_amdgcn_mfma_f32_16x16x32_bf16(a1c, bc[nb], acc[1][nb], 0, 0, 0);
    }
    a0c = a0n; a1c = a1n;
    #pragma unroll
    for (int nb = 0; nb < 4; nb++) bc[nb] = bn[nb];
  }
  #pragma unroll
  for (int nb = 0; nb < 4; nb++){
    int col = nt * 128 + wn * 64 + nb * 16 + rc;
    float bw = b_word[col];
    #pragma unroll
    for (int h = 0; h < 2; h++){
      #pragma unroll
      for (int q = 0; q < 4; q++){
        int row = mt * 64 + wm * 32 + h * 16 + lg * 4 + q;
        float v = acc[h][nb][q] + bw;
        if (col < Hn) HB[(size_t)row * Hn + col] = f2bf(v);
        else          CF[(size_t)row * Hn + (col - Hn)] = v;
      }
    }
  }
}

// ---------------- big-level tile: 64 rows x 16 u, full K per wave (r12/r15 form) ----------------
template<bool LDSB>
static __device__ __forceinline__ void tile64(
    int u0, int t, int nr, const int* __restrict__ sL, const int* __restrict__ sR,
    const int* __restrict__ dl,
    unsigned short* __restrict__ HB, float* __restrict__ CF,
    const unsigned short* __restrict__ WT, const float* __restrict__ b_red,
    const unsigned short* __restrict__ wlds, int rc, int lg)
{
  int base = t * 64;
  int offL[4], offR[4];
  #pragma unroll
  for (int m = 0; m < 4; m++){
    int i = min(base + m * 16 + rc, nr - 1);
    offL[m] = sL[i]; offR[m] = sR[i];
  }
  f32x4 acc[5][4];
  #pragma unroll
  for (int g = 0; g < 5; g++)
    #pragma unroll
    for (int m = 0; m < 4; m++) acc[g][m] = (f32x4){0.f,0.f,0.f,0.f};

  int bswz = (rc & 7) << 3;
  const unsigned short* gb = WT + (size_t)(u0 + rc) * 1024 + lg * 8;

  bf16x8 a_cur[4], b_cur[3];
  #pragma unroll
  for (int m = 0; m < 4; m++) a_cur[m] = *(const bf16x8*)(HB + offL[m] + lg * 8);
  #pragma unroll
  for (int g = 0; g < 3; g++)
    b_cur[g] = *(const bf16x8*)(gb + (size_t)(g + 2) * GATE_STRIDE);

  #pragma unroll 4
  for (int j = 0; j < 32; ++j){
    bf16x8 a_nxt[4], b_nxt[3];
    if (j < 31){
      int kn = (j + 1) * 32 + lg * 8;
      #pragma unroll
      for (int m = 0; m < 4; m++){
        const unsigned short* ap = (j + 1 < 16) ? (HB + offL[m] + kn) : (HB + offR[m] + (kn - 512));
        a_nxt[m] = *(const bf16x8*)ap;
      }
      #pragma unroll
      for (int g = 0; g < 3; g++)
        b_nxt[g] = *(const bf16x8*)(gb + (size_t)(g + 2) * GATE_STRIDE + (j + 1) * 32);
    }
    int k = j * 32 + lg * 8;
    #pragma unroll
    for (int g = 0; g < 2; g++){
      bf16x8 bb;
      if (LDSB) bb = *(const bf16x8*)&wlds[(size_t)(g * 16 + rc) * 1024 + (k ^ bswz)];
      else      bb = *(const bf16x8*)(gb + (size_t)g * GATE_STRIDE + j * 32);
      #pragma unroll
      for (int m = 0; m < 4; m++)
        acc[g][m] = __builtin_amdgcn_mfma_f32_16x16x32_bf16(a_cur[m], bb, acc[g][m], 0, 0, 0);
    }
    #pragma unroll
    for (int g = 0; g < 3; g++){
      #pragma unroll
      for (int m = 0; m < 4; m++)
        acc[g + 2][m] = __builtin_amdgcn_mfma_f32_16x16x32_bf16(a_cur[m], b_cur[g], acc[g + 2][m], 0, 0, 0);
    }
    #pragma unroll
    for (int m = 0; m < 4; m++) a_cur[m] = a_nxt[m];
    #pragma unroll
    for (int g = 0; g < 3; g++) b_cur[g] = b_nxt[g];
  }
  int colu = u0 + rc;
  float bs[5];
  #pragma unroll
  for (int g = 0; g < 5; g++) bs[g] = b_red[g * Hn + colu];
  #pragma unroll
  for (int m = 0; m < 4; m++){
    #pragma unroll
    for (int q = 0; q < 4; q++){
      int i = base + m * 16 + lg * 4 + q;
      if (i < nr){
        int oL = sL[i], oR = sR[i], oD = dl[i];
        float gv = tanh_fast(acc[0][m][q] + bs[0]);
        float iv = sigm(acc[1][m][q] + bs[1]);
        float f1 = sigm(acc[2][m][q] + bs[2]);
        float f2 = sigm(acc[3][m][q] + bs[3]);
        float ov = sigm(acc[4][m][q] + bs[4]);
        float cl = __builtin_nontemporal_load(CF + oL + colu);
        float cr = __builtin_nontemporal_load(CF + oR + colu);
        float cv = gv * iv + f1 * cl + f2 * cr;
        float hv = ov * tanh_fast(cv);
        __builtin_nontemporal_store(cv, CF + oD + colu);
        HB[oD + colu] = f2bf(hv);
      }
    }
  }
}

// ---------------- small-level tile: 16 rows x 16 u, K split over 4 waves ----------------
// FULL preload: all 8 A frags + all 24 streamed-B frags issued upfront (static
// addresses; one ~800cy latency instead of 8 serial). CF early. 4-sync combine.
static __device__ __forceinline__ void tile16(
    int u0, int t, int nr, const int* __restrict__ sL, const int* __restrict__ sR,
    const int* __restrict__ dl,
    unsigned short* __restrict__ HB, float* __restrict__ CF,
    const unsigned short* __restrict__ WT, const float* __restrict__ b_red,
    const unsigned short* __restrict__ wlds, float (*part)[3][16][20],
    int tid, int w, int rc, int lg,
    bool up, int pre_offA, int pre_oL, int pre_oR, int pre_oD)
{
  int base = t * 16;
  int er = tid >> 4, eu = tid & 15;
  int offA, oL, oR, oD;
  if (up){
    offA = pre_offA; oL = pre_oL; oR = pre_oR; oD = pre_oD;
  } else {
    int i0 = min(base + rc, nr - 1);
    offA = (w >= 2) ? sR[i0] : sL[i0];
    int ie = min(base + er, nr - 1);
    oL = sL[ie]; oR = sR[ie]; oD = dl[ie];
  }
  int colu = u0 + eu;
  float cl = __builtin_nontemporal_load(CF + oL + colu);
  float cr = __builtin_nontemporal_load(CF + oR + colu);

  int k0 = w * 256;                       // this wave's K quarter (of 1024)
  int abase = (w >= 2) ? (k0 - 512) : k0; // child-local K offset
  const unsigned short* ap = HB + offA + abase + lg * 8;
  int bswz = (rc & 7) << 3;
  const unsigned short* gb = WT + (size_t)(u0 + rc) * 1024;

  // full A preload (8 frags)
  bf16x8 aF[8];
  #pragma unroll
  for (int j = 0; j < 8; ++j) aF[j] = *(const bf16x8*)(ap + j * 32);
  // full streamed-B preload (gates 2-4, 24 frags)
  bf16x8 bF[8][3];
  #pragma unroll
  for (int j = 0; j < 8; ++j)
    #pragma unroll
    for (int g = 0; g < 3; g++)
      bF[j][g] = *(const bf16x8*)(gb + (size_t)(g + 2) * GATE_STRIDE + k0 + j * 32 + lg * 8);

  f32x4 acc[5];
  #pragma unroll
  for (int g = 0; g < 5; g++) acc[g] = (f32x4){0.f,0.f,0.f,0.f};

  #pragma unroll
  for (int j = 0; j < 8; ++j){
    int k = k0 + j * 32 + lg * 8;
    #pragma unroll
    for (int g = 0; g < 2; g++){
      bf16x8 bb = *(const bf16x8*)&wlds[(size_t)(g * 16 + rc) * 1024 + (k ^ bswz)];
      acc[g] = __builtin_amdgcn_mfma_f32_16x16x32_bf16(aF[j], bb, acc[g], 0, 0, 0);
    }
    #pragma unroll
    for (int g = 0; g < 3; g++)
      acc[g + 2] = __builtin_amdgcn_mfma_f32_16x16x32_bf16(aF[j], bF[j][g], acc[g + 2], 0, 0, 0);
  }
  // combine across waves: round 0 gates 0-2, round 1 gates 3-4 (4 syncs total)
  float sg[5];
  #pragma unroll
  for (int g = 0; g < 3; g++)
    #pragma unroll
    for (int q = 0; q < 4; q++) part[w][g][lg * 4 + q][rc] = acc[g][q];
  __syncthreads();
  #pragma unroll
  for (int g = 0; g < 3; g++)
    sg[g] = part[0][g][er][eu] + part[1][g][er][eu] + part[2][g][er][eu] + part[3][g][er][eu];
  __syncthreads();
  #pragma unroll
  for (int g = 0; g < 2; g++)
    #pragma unroll
    for (int q = 0; q < 4; q++) part[w][g][lg * 4 + q][rc] = acc[3 + g][q];
  __syncthreads();
  #pragma unroll
  for (int g = 0; g < 2; g++)
    sg[3 + g] = part[0][g][er][eu] + part[1][g][er][eu] + part[2][g][er][eu] + part[3][g][er][eu];

  int i = base + er;
  if (i < nr){
    float gv = tanh_fast(sg[0] + b_red[colu]);
    float iv = sigm(sg[1] + b_red[Hn + colu]);
    float f1 = sigm(sg[2] + b_red[2 * Hn + colu]);
    float f2 = sigm(sg[3] + b_red[3 * Hn + colu]);
    float ov = sigm(sg[4] + b_red[4 * Hn + colu]);
    float cv = gv * iv + f1 * cl + f2 * cr;
    float hv = ov * tanh_fast(cv);
    __builtin_nontemporal_store(cv, CF + oD + colu);
    HB[oD + colu] = f2bf(hv);
  }
  __syncthreads();
}

// ---------------- persistent XCD-sharded tree kernel ----------------
extern __shared__ char dynbuf[];

__global__ __launch_bounds__(256)
__attribute__((amdgpu_waves_per_eu(2, 2)))
void tree_kernel(
    unsigned short* __restrict__ HB, float* __restrict__ CF,
    const unsigned short* __restrict__ WT, const float* __restrict__ b_red,
    const int* __restrict__ srcL, const int* __restrict__ srcR,
    const int* __restrict__ dstv, const int* __restrict__ cnt,
    const int* __restrict__ outsrc, float* __restrict__ out, int* bar){
  unsigned short* wlds = (unsigned short*)dynbuf;             // 64KB: gates 0-1
  float (*part)[3][16][20] = (float(*)[3][16][20])(dynbuf + WLDS_BYTES);
  int bid = blockIdx.x;
  int tid = threadIdx.x, w = tid >> 6, lane = tid & 63;
  int rc = lane & 15, lg = lane >> 4;
  int er = tid >> 4;

  int x = xcc_id();
  if (tid == 0){
    int r = __hip_atomic_fetch_add(&bar[OFF_CENSUS + x * FPAD], 1,
                                   __ATOMIC_RELAXED, __HIP_MEMORY_SCOPE_AGENT);
    __hip_atomic_store(&bar[OFF_RANK + bid * FPAD], r, __ATOMIC_RELAXED, __HIP_MEMORY_SCOPE_AGENT);
  }
  __syncthreads();
  int rank = min(__hip_atomic_load(&bar[OFF_RANK + bid * FPAD], __ATOMIC_RELAXED, __HIP_MEMORY_SCOPE_AGENT),
                 MAXRANK - 1);
  int ub = rank & 31;
  int u0 = ub * 16;

  // stage gates 0-1 of this u-block into LDS (XOR-swizzled k)
  for (int gg = tid; gg < 4096; gg += 256){
    int row = gg >> 7;                 // g*16 + u, 0..31
    int k = (gg & 127) * 8;
    int u = row & 15, g = row >> 4;
    bf16x8 v = *(const bf16x8*)(WT + (size_t)(g * 512 + u0 + u) * 1024 + k);
    int kx = k ^ ((u & 7) << 3);
    *(bf16x8*)&wlds[(size_t)row * 1024 + kx] = v;
  }
  __syncthreads();

  // global start barrier so census counts are final
  {
    int* sfl  = bar + OFF_SFLAG;
    int* sgen = bar + OFF_SGEN;
    if (bid == 0){
      for (int i = tid; i < NBLK; i += 256){
        if (i){
          int c = 0;
          while (__hip_atomic_load(&sfl[i * FPAD], __ATOMIC_RELAXED, __HIP_MEMORY_SCOPE_AGENT) == 0 && c < SPIN_CAP){
            __builtin_amdgcn_s_sleep(1); ++c;
          }
        }
      }
      __syncthreads();
      if (tid == 0) __hip_atomic_store(sgen, 1, __ATOMIC_RELAXED, __HIP_MEMORY_SCOPE_AGENT);
    } else {
      if (tid == 0){
        __hip_atomic_store(&sfl[bid * FPAD], 1, __ATOMIC_RELAXED, __HIP_MEMORY_SCOPE_AGENT);
        int c = 0;
        while (__hip_atomic_load(sgen, __ATOMIC_RELAXED, __HIP_MEMORY_SCOPE_AGENT) == 0 && c < SPIN_CAP){
          __builtin_amdgcn_s_sleep(2); ++c;
        }
      }
      __syncthreads();
    }
  }
  int nx = max(__hip_atomic_load(&bar[OFF_CENSUS + x * FPAD], __ATOMIC_RELAXED, __HIP_MEMORY_SCOPE_AGENT), 1);

  int maxlvl = cnt[NXCD * NLVL + x];
  int epoch = 1;
  int pre_offA = 0, pre_oL = 0, pre_oR = 0, pre_oD = 0;
  bool have_pre = false;
  for (int lvl = 1; lvl <= maxlvl; ++lvl, ++epoch){
    int nr = cnt[x * NLVL + lvl];
    const int* sL = srcL + (x * NLVL + lvl) * CAPX;
    const int* sR = srcR + (x * NLVL + lvl) * CAPX;
    const int* dl = dstv + (x * NLVL + lvl) * CAPX;
    int stripe = rank >> 5;
    if (nr > 0){
      if (nx >= 32){
        int nstr = (nx - 1 - ub) / 32 + 1;     // blocks sharing this ub
        if (nr >= 128){
          int ntl = (nr + 63) >> 6;
          for (int t = stripe * 4 + w; t < ntl; t += nstr * 4)
            tile64<true>(u0, t, nr, sL, sR, dl, HB, CF, WT, b_red, wlds, rc, lg);
        } else {
          int ntl16 = (nr + 15) >> 4;
          for (int t = stripe; t < ntl16; t += nstr)
            tile16(u0, t, nr, sL, sR, dl, HB, CF, WT, b_red, wlds, part, tid, w, rc, lg,
                   have_pre && (t == stripe), pre_offA, pre_oL, pre_oR, pre_oD);
        }
      } else {
        // rare fallback: cover all 32 u-blocks from global
        int ntl = (nr + 63) >> 6;
        int nwv = nx * 4, wid = rank * 4 + w;
        int ntask = ntl * 32;
        for (int task = wid; task < ntask; task += nwv)
          tile64<false>((task / ntl) * 16, task % ntl, nr, sL, sR, dl, HB, CF, WT, b_red, wlds, rc, lg);
      }
    }
    // pre-barrier preload of next level's first-tile indices (static data; safe)
    have_pre = false;
    if (lvl < maxlvl && nx >= 32){
      int nr2 = cnt[x * NLVL + lvl + 1];
      if (nr2 > 0 && nr2 < 128){
        const int* sL2 = srcL + (x * NLVL + lvl + 1) * CAPX;
        const int* sR2 = srcR + (x * NLVL + lvl + 1) * CAPX;
        const int* dl2 = dstv + (x * NLVL + lvl + 1) * CAPX;
        int ntl2 = (nr2 + 15) >> 4;
        if (stripe < ntl2){
          int i0 = min(stripe * 16 + rc, nr2 - 1);
          pre_offA = (w >= 2) ? sR2[i0] : sL2[i0];
          int ie = min(stripe * 16 + er, nr2 - 1);
          pre_oL = sL2[ie]; pre_oR = sR2[ie]; pre_oD = dl2[ie];
          have_pre = true;
        }
      }
    }
    xcd_barrier(bar, x, rank, nx, epoch);
  }

  // final gather for this XCD's 16 trees
  for (int j = rank; j < 16; j += min(nx, MAXRANK)){
    int b = x + 8 * j;
    int src = outsrc[b];
    out[b * Hn + tid]       = bf2f(HB[src + tid]);
    out[b * Hn + tid + 256] = bf2f(HB[src + tid + 256]);
  }
}

// ---------------- launch ----------------
extern "C" void kernel_launch(void* const* d_in, const int* in_sizes, int n_in,
                              void* d_out, int out_size, void* d_ws, size_t ws_size,
                              hipStream_t stream){
  (void)in_sizes; (void)n_in; (void)out_size; (void)ws_size;
  const float* sentence = (const float*)d_in[0];
  const int*   trans    = (const int*)d_in[1];
  const float* W_word   = (const float*)d_in[2];
  const float* b_word   = (const float*)d_in[3];
  const float* W_left   = (const float*)d_in[4];
  const float* W_right  = (const float*)d_in[5];
  const float* b_red    = (const float*)d_in[6];

  char* ws = (char*)d_ws;
  size_t off = 0;
  auto alloc = [&](size_t bytes) -> void* {
    void* p = ws + off;
    off += (bytes + 255) & ~((size_t)255);
    return p;
  };
  unsigned short* HB  = (unsigned short*)alloc((size_t)TOT_ROWS * Hn * 2);
  float*          CF  = (float*)alloc((size_t)TOT_ROWS * Hn * 4);
  unsigned short* WT  = (unsigned short*)alloc((size_t)2560 * 1024 * 2);
  unsigned short* SB  = (unsigned short*)alloc((size_t)LEAF_ROWS * En * 2);
  unsigned short* WwT = (unsigned short*)alloc((size_t)1024 * En * 2);
  int* srcL   = (int*)alloc((size_t)NXCD * NLVL * CAPX * 4);
  int* srcR   = (int*)alloc((size_t)NXCD * NLVL * CAPX * 4);
  int* dstv   = (int*)alloc((size_t)NXCD * NLVL * CAPX * 4);
  int* cnt    = (int*)alloc((size_t)(NXCD * NLVL + NXCD) * 4);
  int* outsrc = (int*)alloc((size_t)Bn * 4);
  int* bar    = (int*)alloc((size_t)BAR_INTS * 4);
  float* outp = (float*)d_out;

  hipFuncSetAttribute(reinterpret_cast<const void*>(tree_kernel),
                      hipFuncAttributeMaxDynamicSharedMemorySize, DYN_BYTES);

  cvt_vec4<<<(LEAF_ROWS * En / 4) / 256, 256, 0, stream>>>((const float4*)sentence, (ushort4*)SB, LEAF_ROWS * En / 4);
  transpose_cvt<<<dim3(1024 / 32, En / 32), dim3(32, 8), 0, stream>>>(W_word, WwT, 1024, En, 0);
  transpose_cvt<<<dim3(2560 / 32, Hn / 32), dim3(32, 8), 0, stream>>>(W_left, WT, 2560, 1024, 0);
  transpose_cvt<<<dim3(2560 / 32, Hn / 32), dim3(32, 8), 0, stream>>>(W_right, WT, 2560, 1024, 512);
  precompute_ctrl<<<1, 128, 0, stream>>>(trans, srcL, srcR, dstv, cnt, outsrc, bar);
  word_gemm<<<dim3(128, 8), 256, 0, stream>>>(SB, WwT, b_word, HB, CF);
  tree_kernel<<<NBLK, 256, DYN_BYTES, stream>>>(HB, CF, WT, b_red, srcL, srcR, dstv, cnt, outsrc, outp, bar);
}

// Round 18
// 598.057 us; speedup vs baseline: 1.4449x; 1.2141x over previous
//
#include <hip/hip_runtime.h>
#include <hip/hip_bf16.h>

// SPINN: word GEMM + XCD-sharded persistent TreeLSTM.
// r18 = r12 verbatim (measured best: 597us total / 497us tree, no spill).
// Weights: gates 0-1 LDS-resident per u-block (64KB, XOR-swizzled); gates 2-4
// streamed from L2. NT CF traffic (read-once) keeps streamed gates L2-resident.
// 512 blocks = 2/CU, 2 blocks per u-block. Fence-free per-XCD barriers.
// Lesson from r13/r14/r17: VGPR allocator is pinned at 128 here; deeper
// prefetch/preload schemes spill to scratch and regress (+100-200us).
// B=128, L=64, E=512, H=512, T=127.

#define Bn 128
#define Ln 64
#define En 512
#define Hn 512
#define Tn 127
#define LEAF_ROWS (Bn*Ln)
#define NODE_ROWS (Bn*(Ln-1))
#define TOT_ROWS (LEAF_ROWS+NODE_ROWS)
#define NLVL 64
#define NXCD 8
#define CAPX 512                 // max rows per XCD-bin per level
#define NBLK 512                 // 2 blocks/CU
#define FPAD 16
#define MAXRANK 96
#define SPIN_CAP (1<<22)
#define GATE_STRIDE (512*1024)
#define WLDS_BYTES 65536         // 2 gates x 16u x 1024k x 2B
#define PART_BYTES (4*2*16*20*4) // [wave][gatepair][row][col+pad] f32
#define DYN_BYTES (WLDS_BYTES + PART_BYTES)

// barrier/census state layout (ints), zeroed by precompute_ctrl each call
#define OFF_CENSUS 0                              // NXCD*FPAD
#define OFF_RANK   (OFF_CENSUS + NXCD*FPAD)       // NBLK*FPAD
#define OFF_SFLAG  (OFF_RANK + NBLK*FPAD)         // NBLK*FPAD
#define OFF_SGEN   (OFF_SFLAG + NBLK*FPAD)        // FPAD
#define OFF_FX     (OFF_SGEN + FPAD)              // NXCD*MAXRANK*FPAD
#define OFF_GX     (OFF_FX + NXCD*MAXRANK*FPAD)   // NXCD*FPAD
#define BAR_INTS   (OFF_GX + NXCD*FPAD)

typedef __attribute__((ext_vector_type(8))) short bf16x8;
typedef __attribute__((ext_vector_type(4))) float f32x4;

static __device__ __forceinline__ float bf2f(unsigned short u){
  unsigned v = ((unsigned)u) << 16;
  float f; __builtin_memcpy(&f, &v, 4); return f;
}
static __device__ __forceinline__ unsigned short f2bf(float f){
  unsigned u; __builtin_memcpy(&u, &f, 4);
  u = u + 0x7FFFu + ((u >> 16) & 1u);   // round-nearest-even
  return (unsigned short)(u >> 16);
}
static __device__ __forceinline__ float sigm(float x){
  return 1.0f / (1.0f + __expf(-x));
}
static __device__ __forceinline__ float tanh_fast(float x){
  x = fminf(fmaxf(x, -15.0f), 15.0f);
  float t = __expf(2.0f * x);
  return (t - 1.0f) / (t + 1.0f);
}
static __device__ __forceinline__ int xcc_id(){
  unsigned v;
  asm volatile("s_getreg_b32 %0, hwreg(HW_REG_XCC_ID)" : "=s"(v));
  return (int)(v & 7);
}

// Per-XCD fence-free barrier (r7-proven).
static __device__ __forceinline__ void xcd_barrier(int* bar, int x, int rank, int nx, int epoch){
  __syncthreads();
  int* fx = bar + OFF_FX + x * MAXRANK * FPAD;
  int* gx = bar + OFF_GX + x * FPAD;
  int nxl = min(nx, MAXRANK);
  if (rank == 0){
    for (int i = threadIdx.x + 1; i < nxl; i += 256){
      int c = 0;
      while (__hip_atomic_load(&fx[i * FPAD], __ATOMIC_RELAXED, __HIP_MEMORY_SCOPE_AGENT) < epoch && c < SPIN_CAP){
        __builtin_amdgcn_s_sleep(1); ++c;
      }
    }
    __syncthreads();
    if (threadIdx.x == 0)
      __hip_atomic_store(gx, epoch, __ATOMIC_RELAXED, __HIP_MEMORY_SCOPE_AGENT);
  } else {
    if (threadIdx.x == 0){
      __hip_atomic_store(&fx[rank * FPAD], epoch, __ATOMIC_RELAXED, __HIP_MEMORY_SCOPE_AGENT);
      int c = 0;
      while (__hip_atomic_load(gx, __ATOMIC_RELAXED, __HIP_MEMORY_SCOPE_AGENT) < epoch && c < SPIN_CAP){
        __builtin_amdgcn_s_sleep(2); ++c;
      }
    }
    __syncthreads();
  }
  asm volatile("" ::: "memory");
}

// ---------------- convert / transpose helpers ----------------

__global__ void cvt_vec4(const float4* __restrict__ x, ushort4* __restrict__ y, int n4){
  int i = blockIdx.x * 256 + threadIdx.x;
  if (i < n4){
    float4 v = x[i];
    ushort4 o;
    o.x = f2bf(v.x); o.y = f2bf(v.y); o.z = f2bf(v.z); o.w = f2bf(v.w);
    y[i] = o;
  }
}

__global__ void transpose_cvt(const float* __restrict__ src, unsigned short* __restrict__ dstT,
                              int CS, int DS, int koff){
  __shared__ float tile[32][33];
  int c0 = blockIdx.x * 32, r0 = blockIdx.y * 32;
  int tx = threadIdx.x, ty = threadIdx.y;
  for (int i = ty; i < 32; i += 8) tile[i][tx] = src[(size_t)(r0 + i) * CS + c0 + tx];
  __syncthreads();
  for (int i = ty; i < 32; i += 8)
    dstT[(size_t)(c0 + i) * DS + koff + r0 + tx] = f2bf(tile[tx][i]);
}

// ---------------- control precompute ----------------
__global__ void precompute_ctrl(const int* __restrict__ trans,
                                int* __restrict__ srcL, int* __restrict__ srcR,
                                int* __restrict__ dstv, int* __restrict__ cnt,
                                int* __restrict__ outsrc, int* __restrict__ bar){
  __shared__ int stk[Bn][Ln + 1];
  __shared__ int scnt[NXCD * NLVL];
  __shared__ int smaxl[NXCD];
  int b = threadIdx.x;
  for (int i = b; i < NXCD * NLVL; i += 128) scnt[i] = 0;
  if (b < NXCD) smaxl[b] = 0;
  for (int i = b; i < BAR_INTS; i += 128) bar[i] = 0;
  __syncthreads();
  int x = b & 7;
  int sp = 0, bp = 0, nodecnt = 0;
  int act_next = trans[b * Tn];
  for (int t = 0; t < Tn; t++){
    int act = act_next;
    if (t + 1 < Tn) act_next = trans[b * Tn + t + 1];
    int ops = Tn - t;
    if (sp > ops) act = 2;                       // forced REDUCE (matches ref)
    if (act == 2){
      int R = stk[b][sp - 1], L = stk[b][sp - 2];
      int lvl = max(R >> 20, L >> 20) + 1;
      int slot = atomicAdd(&scnt[x * NLVL + lvl], 1);
      int base = (x * NLVL + lvl) * CAPX + slot;
      srcL[base] = (L & 0xFFFFF) * Hn;
      srcR[base] = (R & 0xFFFFF) * Hn;
      int noderow = LEAF_ROWS + b * (Ln - 1) + nodecnt;
      dstv[base] = noderow * Hn;
      stk[b][sp - 2] = noderow | (lvl << 20);
      sp -= 1; nodecnt++;
    } else {
      stk[b][sp] = b * Ln + min(bp, Ln - 1);
      sp += 1; bp += 1;
    }
  }
  int root = stk[b][max(sp - 1, 0)];
  outsrc[b] = (root & 0xFFFFF) * Hn;
  atomicMax(&smaxl[x], root >> 20);
  __syncthreads();
  for (int i = b; i < NXCD * NLVL; i += 128) cnt[i] = scnt[i];
  if (b < NXCD) cnt[NXCD * NLVL + b] = smaxl[b];
}

// ---------------- word GEMM ----------------
__global__ __launch_bounds__(256) void word_gemm(
    const unsigned short* __restrict__ SB, const unsigned short* __restrict__ WwT,
    const float* __restrict__ b_word,
    unsigned short* __restrict__ HB, float* __restrict__ CF){
  int nt = blockIdx.x;
  int mt = blockIdx.y;
  int tid = threadIdx.x, w = tid >> 6, lane = tid & 63;
  int wm = w >> 1, wn = w & 1;
  int rc = lane & 15, lg = lane >> 4;
  const unsigned short* ap0 = SB + (size_t)(mt * 64 + wm * 32 + rc) * En + lg * 8;
  const unsigned short* ap1 = ap0 + (size_t)16 * En;
  const unsigned short* bp0 = WwT + (size_t)(nt * 128 + wn * 64 + rc) * En + lg * 8;
  f32x4 acc[2][4];
  #pragma unroll
  for (int h = 0; h < 2; h++)
    #pragma unroll
    for (int nb = 0; nb < 4; nb++) acc[h][nb] = (f32x4){0.f,0.f,0.f,0.f};

  bf16x8 aS0[3], aS1[3], bS[4][3];
  #pragma unroll
  for (int s = 0; s < 2; s++){
    aS0[s] = *(const bf16x8*)(ap0 + s * 32);
    aS1[s] = *(const bf16x8*)(ap1 + s * 32);
    #pragma unroll
    for (int nb = 0; nb < 4; nb++)
      bS[nb][s] = *(const bf16x8*)(bp0 + (size_t)nb * 16 * En + s * 32);
  }
  #pragma unroll
  for (int j = 0; j < 16; ++j){
    const int cur = j % 3, n2 = (j + 2) % 3;
    if (j < 14){
      int kn = (j + 2) * 32;
      aS0[n2] = *(const bf16x8*)(ap0 + kn);
      aS1[n2] = *(const bf16x8*)(ap1 + kn);
      #pragma unroll
      for (int nb = 0; nb < 4; nb++)
        bS[nb][n2] = *(const bf16x8*)(bp0 + (size_t)nb * 16 * En + kn);
    }
    #pragma unroll
    for (int nb = 0; nb < 4; nb++){
      acc[0][nb] = __builtin_amdgcn_mfma_f32_16x16x32_bf16(aS0[cur], bS[nb][cur], acc[0][nb], 0, 0, 0);
      acc[1][nb] = __builtin_amdgcn_mfma_f32_16x16x32_bf16(aS1[cur], bS[nb][cur], acc[1][nb], 0, 0, 0);
    }
  }
  #pragma unroll
  for (int nb = 0; nb < 4; nb++){
    int col = nt * 128 + wn * 64 + nb * 16 + rc;
    float bw = b_word[col];
    #pragma unroll
    for (int h = 0; h < 2; h++){
      #pragma unroll
      for (int q = 0; q < 4; q++){
        int row = mt * 64 + wm * 32 + h * 16 + lg * 4 + q;
        float v = acc[h][nb][q] + bw;
        if (col < Hn) HB[(size_t)row * Hn + col] = f2bf(v);
        else          CF[(size_t)row * Hn + (col - Hn)] = v;
      }
    }
  }
}

// ---------------- big-level tile: 64 rows x 16 u, full K per wave ----------------
// Gates 0-1 LDS (swizzled); gates 2-4 global PF1; A PF1; CF NT loads in the
// epilogue (no spill).
template<bool LDSB>
static __device__ __forceinline__ void tile64(
    int u0, int t, int nr, const int* __restrict__ sL, const int* __restrict__ sR,
    const int* __restrict__ dl,
    unsigned short* __restrict__ HB, float* __restrict__ CF,
    const unsigned short* __restrict__ WT, const float* __restrict__ b_red,
    const unsigned short* __restrict__ wlds, int rc, int lg)
{
  int base = t * 64;
  int offL[4], offR[4];
  #pragma unroll
  for (int m = 0; m < 4; m++){
    int i = min(base + m * 16 + rc, nr - 1);
    offL[m] = sL[i]; offR[m] = sR[i];
  }
  f32x4 acc[5][4];
  #pragma unroll
  for (int g = 0; g < 5; g++)
    #pragma unroll
    for (int m = 0; m < 4; m++) acc[g][m] = (f32x4){0.f,0.f,0.f,0.f};

  int bswz = (rc & 7) << 3;
  const unsigned short* gb = WT + (size_t)(u0 + rc) * 1024 + lg * 8;

  bf16x8 a_cur[4], b_cur[3];
  #pragma unroll
  for (int m = 0; m < 4; m++) a_cur[m] = *(const bf16x8*)(HB + offL[m] + lg * 8);
  #pragma unroll
  for (int g = 0; g < 3; g++)
    b_cur[g] = *(const bf16x8*)(gb + (size_t)(g + 2) * GATE_STRIDE);

  #pragma unroll 4
  for (int j = 0; j < 32; ++j){
    bf16x8 a_nxt[4], b_nxt[3];
    if (j < 31){
      int kn = (j + 1) * 32 + lg * 8;
      #pragma unroll
      for (int m = 0; m < 4; m++){
        const unsigned short* ap = (j + 1 < 16) ? (HB + offL[m] + kn) : (HB + offR[m] + (kn - 512));
        a_nxt[m] = *(const bf16x8*)ap;
      }
      #pragma unroll
      for (int g = 0; g < 3; g++)
        b_nxt[g] = *(const bf16x8*)(gb + (size_t)(g + 2) * GATE_STRIDE + (j + 1) * 32);
    }
    int k = j * 32 + lg * 8;
    #pragma unroll
    for (int g = 0; g < 2; g++){
      bf16x8 bb;
      if (LDSB) bb = *(const bf16x8*)&wlds[(size_t)(g * 16 + rc) * 1024 + (k ^ bswz)];
      else      bb = *(const bf16x8*)(gb + (size_t)g * GATE_STRIDE + j * 32);
      #pragma unroll
      for (int m = 0; m < 4; m++)
        acc[g][m] = __builtin_amdgcn_mfma_f32_16x16x32_bf16(a_cur[m], bb, acc[g][m], 0, 0, 0);
    }
    #pragma unroll
    for (int g = 0; g < 3; g++){
      #pragma unroll
      for (int m = 0; m < 4; m++)
        acc[g + 2][m] = __builtin_amdgcn_mfma_f32_16x16x32_bf16(a_cur[m], b_cur[g], acc[g + 2][m], 0, 0, 0);
    }
    #pragma unroll
    for (int m = 0; m < 4; m++) a_cur[m] = a_nxt[m];
    #pragma unroll
    for (int g = 0; g < 3; g++) b_cur[g] = b_nxt[g];
  }
  // lane-local LSTM epilogue: C/D row = lg*4+q, col = rc
  int colu = u0 + rc;
  float bs[5];
  #pragma unroll
  for (int g = 0; g < 5; g++) bs[g] = b_red[g * Hn + colu];
  #pragma unroll
  for (int m = 0; m < 4; m++){
    #pragma unroll
    for (int q = 0; q < 4; q++){
      int i = base + m * 16 + lg * 4 + q;
      if (i < nr){
        int oL = sL[i], oR = sR[i], oD = dl[i];
        float gv = tanh_fast(acc[0][m][q] + bs[0]);
        float iv = sigm(acc[1][m][q] + bs[1]);
        float f1 = sigm(acc[2][m][q] + bs[2]);
        float f2 = sigm(acc[3][m][q] + bs[3]);
        float ov = sigm(acc[4][m][q] + bs[4]);
        float cl = __builtin_nontemporal_load(CF + oL + colu);
        float cr = __builtin_nontemporal_load(CF + oR + colu);
        float cv = gv * iv + f1 * cl + f2 * cr;
        float hv = ov * tanh_fast(cv);
        __builtin_nontemporal_store(cv, CF + oD + colu);
        HB[oD + colu] = f2bf(hv);
      }
    }
  }
}

// ---------------- small-level tile: 16 rows x 16 u, K split over 4 waves ----------------
static __device__ __forceinline__ void tile16(
    int u0, int t, int nr, const int* __restrict__ sL, const int* __restrict__ sR,
    const int* __restrict__ dl,
    unsigned short* __restrict__ HB, float* __restrict__ CF,
    const unsigned short* __restrict__ WT, const float* __restrict__ b_red,
    const unsigned short* __restrict__ wlds, float (*part)[2][16][20],
    int tid, int w, int rc, int lg)
{
  int base = t * 16;
  int i0 = min(base + rc, nr - 1);
  int offA = (w >= 2) ? sR[i0] : sL[i0];
  int k0 = w * 256;                       // this wave's K quarter (of 1024)
  int abase = (w >= 2) ? (k0 - 512) : k0; // child-local K offset
  const unsigned short* ap = HB + offA + abase + lg * 8;
  int bswz = (rc & 7) << 3;
  const unsigned short* gb = WT + (size_t)(u0 + rc) * 1024;

  f32x4 acc[5];
  #pragma unroll
  for (int g = 0; g < 5; g++) acc[g] = (f32x4){0.f,0.f,0.f,0.f};

  bf16x8 a_cur = *(const bf16x8*)ap;
  bf16x8 b_cur[3];
  #pragma unroll
  for (int g = 0; g < 3; g++)
    b_cur[g] = *(const bf16x8*)(gb + (size_t)(g + 2) * GATE_STRIDE + k0 + lg * 8);

  #pragma unroll
  for (int j = 0; j < 8; ++j){
    bf16x8 a_nxt, b_nxt[3];
    if (j < 7){
      a_nxt = *(const bf16x8*)(ap + (j + 1) * 32);
      #pragma unroll
      for (int g = 0; g < 3; g++)
        b_nxt[g] = *(const bf16x8*)(gb + (size_t)(g + 2) * GATE_STRIDE + k0 + (j + 1) * 32 + lg * 8);
    }
    int k = k0 + j * 32 + lg * 8;
    #pragma unroll
    for (int g = 0; g < 2; g++){
      bf16x8 bb = *(const bf16x8*)&wlds[(size_t)(g * 16 + rc) * 1024 + (k ^ bswz)];
      acc[g] = __builtin_amdgcn_mfma_f32_16x16x32_bf16(a_cur, bb, acc[g], 0, 0, 0);
    }
    #pragma unroll
    for (int g = 0; g < 3; g++)
      acc[g + 2] = __builtin_amdgcn_mfma_f32_16x16x32_bf16(a_cur, b_cur[g], acc[g + 2], 0, 0, 0);
    a_cur = a_nxt;
    #pragma unroll
    for (int g = 0; g < 3; g++) b_cur[g] = b_nxt[g];
  }
  // combine across waves, gate pairs (LDS [4][2][16][20])
  int er = tid >> 4, eu = tid & 15;
  float sg[5];
  #pragma unroll
  for (int r = 0; r < 3; ++r){
    int ng = (r < 2) ? 2 : 1;
    #pragma unroll
    for (int gi = 0; gi < 2; ++gi){
      if (gi < ng){
        int g = r * 2 + gi;
        #pragma unroll
        for (int q = 0; q < 4; q++) part[w][gi][lg * 4 + q][rc] = acc[g][q];
      }
    }
    __syncthreads();
    #pragma unroll
    for (int gi = 0; gi < 2; ++gi){
      if (gi < ng)
        sg[r * 2 + gi] = part[0][gi][er][eu] + part[1][gi][er][eu]
                       + part[2][gi][er][eu] + part[3][gi][er][eu];
    }
    __syncthreads();
  }
  int i = base + er;
  if (i < nr){
    int colu = u0 + eu;
    int oL = sL[i], oR = sR[i], oD = dl[i];
    float gv = tanh_fast(sg[0] + b_red[colu]);
    float iv = sigm(sg[1] + b_red[Hn + colu]);
    float f1 = sigm(sg[2] + b_red[2 * Hn + colu]);
    float f2 = sigm(sg[3] + b_red[3 * Hn + colu]);
    float ov = sigm(sg[4] + b_red[4 * Hn + colu]);
    float cl = __builtin_nontemporal_load(CF + oL + colu);
    float cr = __builtin_nontemporal_load(CF + oR + colu);
    float cv = gv * iv + f1 * cl + f2 * cr;
    float hv = ov * tanh_fast(cv);
    __builtin_nontemporal_store(cv, CF + oD + colu);
    HB[oD + colu] = f2bf(hv);
  }
  __syncthreads();
}

// ---------------- persistent XCD-sharded tree kernel ----------------
extern __shared__ char dynbuf[];

__global__ __launch_bounds__(256, 2) void tree_kernel(
    unsigned short* __restrict__ HB, float* __restrict__ CF,
    const unsigned short* __restrict__ WT, const float* __restrict__ b_red,
    const int* __restrict__ srcL, const int* __restrict__ srcR,
    const int* __restrict__ dstv, const int* __restrict__ cnt,
    const int* __restrict__ outsrc, float* __restrict__ out, int* bar){
  unsigned short* wlds = (unsigned short*)dynbuf;             // 64KB: gates 0-1
  float (*part)[2][16][20] = (float(*)[2][16][20])(dynbuf + WLDS_BYTES);
  int bid = blockIdx.x;
  int tid = threadIdx.x, w = tid >> 6, lane = tid & 63;
  int rc = lane & 15, lg = lane >> 4;

  int x = xcc_id();
  if (tid == 0){
    int r = __hip_atomic_fetch_add(&bar[OFF_CENSUS + x * FPAD], 1,
                                   __ATOMIC_RELAXED, __HIP_MEMORY_SCOPE_AGENT);
    __hip_atomic_store(&bar[OFF_RANK + bid * FPAD], r, __ATOMIC_RELAXED, __HIP_MEMORY_SCOPE_AGENT);
  }
  __syncthreads();
  int rank = min(__hip_atomic_load(&bar[OFF_RANK + bid * FPAD], __ATOMIC_RELAXED, __HIP_MEMORY_SCOPE_AGENT),
                 MAXRANK - 1);
  int ub = rank & 31;
  int u0 = ub * 16;

  // stage gates 0-1 of this u-block into LDS (XOR-swizzled k)
  for (int gg = tid; gg < 4096; gg += 256){
    int row = gg >> 7;                 // g*16 + u, 0..31
    int k = (gg & 127) * 8;
    int u = row & 15, g = row >> 4;
    bf16x8 v = *(const bf16x8*)(WT + (size_t)(g * 512 + u0 + u) * 1024 + k);
    int kx = k ^ ((u & 7) << 3);
    *(bf16x8*)&wlds[(size_t)row * 1024 + kx] = v;
  }
  __syncthreads();

  // global start barrier so census counts are final
  {
    int* sfl  = bar + OFF_SFLAG;
    int* sgen = bar + OFF_SGEN;
    if (bid == 0){
      for (int i = tid; i < NBLK; i += 256){
        if (i){
          int c = 0;
          while (__hip_atomic_load(&sfl[i * FPAD], __ATOMIC_RELAXED, __HIP_MEMORY_SCOPE_AGENT) == 0 && c < SPIN_CAP){
            __builtin_amdgcn_s_sleep(1); ++c;
          }
        }
      }
      __syncthreads();
      if (tid == 0) __hip_atomic_store(sgen, 1, __ATOMIC_RELAXED, __HIP_MEMORY_SCOPE_AGENT);
    } else {
      if (tid == 0){
        __hip_atomic_store(&sfl[bid * FPAD], 1, __ATOMIC_RELAXED, __HIP_MEMORY_SCOPE_AGENT);
        int c = 0;
        while (__hip_atomic_load(sgen, __ATOMIC_RELAXED, __HIP_MEMORY_SCOPE_AGENT) == 0 && c < SPIN_CAP){
          __builtin_amdgcn_s_sleep(2); ++c;
        }
      }
      __syncthreads();
    }
  }
  int nx = max(__hip_atomic_load(&bar[OFF_CENSUS + x * FPAD], __ATOMIC_RELAXED, __HIP_MEMORY_SCOPE_AGENT), 1);

  int maxlvl = cnt[NXCD * NLVL + x];
  int epoch = 1;
  for (int lvl = 1; lvl <= maxlvl; ++lvl, ++epoch){
    int nr = cnt[x * NLVL + lvl];
    const int* sL = srcL + (x * NLVL + lvl) * CAPX;
    const int* sR = srcR + (x * NLVL + lvl) * CAPX;
    const int* dl = dstv + (x * NLVL + lvl) * CAPX;
    if (nr > 0){
      if (nx >= 32){
        int nstr = (nx - 1 - ub) / 32 + 1;     // blocks sharing this ub
        int stripe = rank >> 5;
        if (nr >= 128){
          int ntl = (nr + 63) >> 6;
          for (int t = stripe * 4 + w; t < ntl; t += nstr * 4)
            tile64<true>(u0, t, nr, sL, sR, dl, HB, CF, WT, b_red, wlds, rc, lg);
        } else {
          int ntl16 = (nr + 15) >> 4;
          for (int t = stripe; t < ntl16; t += nstr)
            tile16(u0, t, nr, sL, sR, dl, HB, CF, WT, b_red, wlds, part, tid, w, rc, lg);
        }
      } else {
        // rare fallback: cover all 32 u-blocks from global
        int ntl = (nr + 63) >> 6;
        int nwv = nx * 4, wid = rank * 4 + w;
        int ntask = ntl * 32;
        for (int task = wid; task < ntask; task += nwv)
          tile64<false>((task / ntl) * 16, task % ntl, nr, sL, sR, dl, HB, CF, WT, b_red, wlds, rc, lg);
      }
    }
    xcd_barrier(bar, x, rank, nx, epoch);
  }

  // final gather for this XCD's 16 trees
  for (int j = rank; j < 16; j += min(nx, MAXRANK)){
    int b = x + 8 * j;
    int src = outsrc[b];
    out[b * Hn + tid]       = bf2f(HB[src + tid]);
    out[b * Hn + tid + 256] = bf2f(HB[src + tid + 256]);
  }
}

// ---------------- launch ----------------
extern "C" void kernel_launch(void* const* d_in, const int* in_sizes, int n_in,
                              void* d_out, int out_size, void* d_ws, size_t ws_size,
                              hipStream_t stream){
  (void)in_sizes; (void)n_in; (void)out_size; (void)ws_size;
  const float* sentence = (const float*)d_in[0];
  const int*   trans    = (const int*)d_in[1];
  const float* W_word   = (const float*)d_in[2];
  const float* b_word   = (const float*)d_in[3];
  const float* W_left   = (const float*)d_in[4];
  const float* W_right  = (const float*)d_in[5];
  const float* b_red    = (const float*)d_in[6];

  char* ws = (char*)d_ws;
  size_t off = 0;
  auto alloc = [&](size_t bytes) -> void* {
    void* p = ws + off;
    off += (bytes + 255) & ~((size_t)255);
    return p;
  };
  unsigned short* HB  = (unsigned short*)alloc((size_t)TOT_ROWS * Hn * 2);
  float*          CF  = (float*)alloc((size_t)TOT_ROWS * Hn * 4);
  unsigned short* WT  = (unsigned short*)alloc((size_t)2560 * 1024 * 2);
  unsigned short* SB  = (unsigned short*)alloc((size_t)LEAF_ROWS * En * 2);
  unsigned short* WwT = (unsigned short*)alloc((size_t)1024 * En * 2);
  int* srcL   = (int*)alloc((size_t)NXCD * NLVL * CAPX * 4);
  int* srcR   = (int*)alloc((size_t)NXCD * NLVL * CAPX * 4);
  int* dstv   = (int*)alloc((size_t)NXCD * NLVL * CAPX * 4);
  int* cnt    = (int*)alloc((size_t)(NXCD * NLVL + NXCD) * 4);
  int* outsrc = (int*)alloc((size_t)Bn * 4);
  int* bar    = (int*)alloc((size_t)BAR_INTS * 4);
  float* outp = (float*)d_out;

  hipFuncSetAttribute(reinterpret_cast<const void*>(tree_kernel),
                      hipFuncAttributeMaxDynamicSharedMemorySize, DYN_BYTES);

  cvt_vec4<<<(LEAF_ROWS * En / 4) / 256, 256, 0, stream>>>((const float4*)sentence, (ushort4*)SB, LEAF_ROWS * En / 4);
  transpose_cvt<<<dim3(1024 / 32, En / 32), dim3(32, 8), 0, stream>>>(W_word, WwT, 1024, En, 0);
  transpose_cvt<<<dim3(2560 / 32, Hn / 32), dim3(32, 8), 0, stream>>>(W_left, WT, 2560, 1024, 0);
  transpose_cvt<<<dim3(2560 / 32, Hn / 32), dim3(32, 8), 0, stream>>>(W_right, WT, 2560, 1024, 512);
  precompute_ctrl<<<1, 128, 0, stream>>>(trans, srcL, srcR, dstv, cnt, outsrc, bar);
  word_gemm<<<dim3(8, LEAF_ROWS / 64), 256, 0, stream>>>(SB, WwT, b_word, HB, CF);
  tree_kernel<<<NBLK, 256, DYN_BYTES, stream>>>(HB, CF, WT, b_red, srcL, srcR, dstv, cnt, outsrc, outp, bar);
}